// Round 5
// baseline (27984.961 us; speedup 1.0000x reference)
//
#include <hip/hip_runtime.h>
#include <math.h>

// KNNGraph(2) on N=16384 points, D=64, fp32.
// adjacency = I + one-hot(nearest other neighbor) per row.
// argmin_j (sq[j] - 2*dot(x_i,x_j)), j != i.
//
// R1-R4 lessons: 26-29 ms invariant across output-store removal, tile-size,
// and register-pressure changes; VALUBusy ~1.8% throughout. Diagnosis: the
// load->LDS->barrier->compute->barrier K-loop serializes full global-load
// latency every tile for every wave, with all blocks in lock-step.
// R5: software-pipelined double-buffered K-loop — prefetch tile jt+1 into
// registers during compute of tile jt, single barrier per tile.

#define NPTS 16384
#define DIM 64
#define BM 64           // rows per block
#define BN 64           // cols per j-tile
#define TM 4            // rows per thread
#define TN 4            // cols per thread
#define NTHR 256        // 16x16 thread layout
#define JSPLIT 8        // grid 2048 blocks; better CU packing at 3 blocks/CU
#define JRANGE (NPTS / JSPLIT)   // 2048
#define NJT (JRANGE / BN)        // 32 tiles
#define LS 68           // B-tile LDS row stride (padding breaks 16-row conflicts)

typedef float floatx4 __attribute__((ext_vector_type(4)));

// ---- 1 GiB zero-fill: contiguous nontemporal 16B stores ----
__global__ void zero_kernel(floatx4* __restrict__ out) {
  size_t base = (size_t)blockIdx.x * 1024 + threadIdx.x;
  const floatx4 z = {0.f, 0.f, 0.f, 0.f};
#pragma unroll
  for (int k = 0; k < 4; ++k)
    __builtin_nontemporal_store(z, &out[base + 256 * k]);
}

__global__ void sq_kernel(const float* __restrict__ X, float* __restrict__ sqout) {
  int i = blockIdx.x * NTHR + threadIdx.x;
  const float4* x4 = (const float4*)(X + (size_t)i * DIM);
  float s = 0.f;
#pragma unroll
  for (int k = 0; k < DIM / 4; ++k) {
    float4 v = x4[k];
    s = fmaf(v.x, v.x, s); s = fmaf(v.y, v.y, s);
    s = fmaf(v.z, v.z, s); s = fmaf(v.w, v.w, s);
  }
  sqout[i] = s;
}

__global__ void knn_kernel(
    const float* __restrict__ X, const float* __restrict__ sqn,
    float* __restrict__ cand_val, int* __restrict__ cand_idx) {
  // A unpadded: a-reads are 16-lane broadcasts (4 addrs/wave) -> conflict-free.
  __shared__ float As[BM * DIM];        // 16384 B
  __shared__ float Bs[2][BN * LS];      // 2 x 17408 B
  __shared__ float sqt[2][BN];          // 2 x 256 B   -> total ~51.7 KB

  const int tid = threadIdx.x;
  const int tx = tid & 15;
  const int ty = tid >> 4;
  const int ib = blockIdx.x >> 3;   // / JSPLIT
  const int jh = blockIdx.x & 7;    // % JSPLIT
  const int i0 = ib * BM;
  const int j0base = jh * JRANGE;

  // Stage A tile (BM x DIM): 4 float4 per thread, coalesced.
  {
    const float4* src = (const float4*)(X + (size_t)i0 * DIM);
#pragma unroll
    for (int p = 0; p < 4; ++p) {
      int f4 = tid + NTHR * p;
      *(float4*)(&As[f4 * 4]) = src[f4];
    }
  }

  // Prefetch tile 0 into registers, then commit to buffer 0.
  float4 pre[4];
  float presq;
  {
    const float4* src = (const float4*)(X + (size_t)j0base * DIM);
#pragma unroll
    for (int p = 0; p < 4; ++p) pre[p] = src[tid + NTHR * p];
    presq = (tid < BN) ? sqn[j0base + tid] : 0.f;
  }
  {
    float* bnxt = &Bs[0][0];
#pragma unroll
    for (int p = 0; p < 4; ++p) {
      int f4 = tid + NTHR * p;
      int r = f4 >> 4, c = f4 & 15;
      *(float4*)(&bnxt[r * LS + c * 4]) = pre[p];
    }
    if (tid < BN) sqt[0][tid] = presq;
  }
  __syncthreads();   // A + tile 0 visible

  float bestv[TM];
  int besti[TM];
#pragma unroll
  for (int mk = 0; mk < TM; ++mk) { bestv[mk] = INFINITY; besti[mk] = 0x7fffffff; }

  for (int jt = 0; jt < NJT; ++jt) {
    const int cur = jt & 1;
    const float* bcur = &Bs[cur][0];
    const float* scur = &sqt[cur][0];

    // Issue prefetch of tile jt+1 (in flight during compute below).
    if (jt + 1 < NJT) {
      const float4* src =
          (const float4*)(X + (size_t)(j0base + (jt + 1) * BN) * DIM);
#pragma unroll
      for (int p = 0; p < 4; ++p) pre[p] = src[tid + NTHR * p];
      presq = (tid < BN) ? sqn[j0base + (jt + 1) * BN + tid] : 0.f;
    }

    float acc[TM][TN];
#pragma unroll
    for (int mk = 0; mk < TM; ++mk)
#pragma unroll
      for (int nk = 0; nk < TN; ++nk) acc[mk][nk] = 0.f;

#pragma unroll
    for (int d0 = 0; d0 < DIM; d0 += 4) {
      float4 a[TM], b[TN];
#pragma unroll
      for (int mk = 0; mk < TM; ++mk)
        a[mk] = *(const float4*)(&As[(ty + 16 * mk) * DIM + d0]);
#pragma unroll
      for (int nk = 0; nk < TN; ++nk)
        b[nk] = *(const float4*)(&bcur[(tx + 16 * nk) * LS + d0]);
#pragma unroll
      for (int mk = 0; mk < TM; ++mk)
#pragma unroll
        for (int nk = 0; nk < TN; ++nk) {
          acc[mk][nk] = fmaf(a[mk].x, b[nk].x, acc[mk][nk]);
          acc[mk][nk] = fmaf(a[mk].y, b[nk].y, acc[mk][nk]);
          acc[mk][nk] = fmaf(a[mk].z, b[nk].z, acc[mk][nk]);
          acc[mk][nk] = fmaf(a[mk].w, b[nk].w, acc[mk][nk]);
        }
    }

    // Argmin update (j increasing per thread across jt).
    const int j0 = j0base + jt * BN;
#pragma unroll
    for (int nk = 0; nk < TN; ++nk) {
      const int j = j0 + tx + 16 * nk;
      const float sj = scur[tx + 16 * nk];
#pragma unroll
      for (int mk = 0; mk < TM; ++mk) {
        const int irow = i0 + ty + 16 * mk;
        float v = fmaf(-2.f, acc[mk][nk], sj);
        if (j != irow && (v < bestv[mk] || (v == bestv[mk] && j < besti[mk]))) {
          bestv[mk] = v;
          besti[mk] = j;
        }
      }
    }

    // Commit prefetched tile to the other buffer (its readers finished at the
    // barrier that ended iteration jt-1).
    if (jt + 1 < NJT) {
      float* bnxt = &Bs[cur ^ 1][0];
#pragma unroll
      for (int p = 0; p < 4; ++p) {
        int f4 = tid + NTHR * p;
        int r = f4 >> 4, c = f4 & 15;
        *(float4*)(&bnxt[r * LS + c * 4]) = pre[p];
      }
      if (tid < BN) sqt[cur ^ 1][tid] = presq;
    }
    __syncthreads();
  }

  // Cross-thread reduction: row m = ty + 16*mk owned by its 16 tx-threads.
  float* rv = As;              // BM*16 floats = 4 KB
  int* ri = (int*)&Bs[0][0];   // BM*16 ints  = 4 KB
#pragma unroll
  for (int mk = 0; mk < TM; ++mk) {
    int m = ty + 16 * mk;
    rv[m * 16 + tx] = bestv[mk];
    ri[m * 16 + tx] = besti[mk];
  }
  __syncthreads();
  if (tid < BM) {
    float bv = INFINITY;
    int bi = 0x7fffffff;
#pragma unroll
    for (int t = 0; t < 16; ++t) {
      float v = rv[tid * 16 + t];
      int ix = ri[tid * 16 + t];
      if (v < bv || (v == bv && ix < bi)) { bv = v; bi = ix; }
    }
    cand_val[(size_t)(i0 + tid) * JSPLIT + jh] = bv;
    cand_idx[(size_t)(i0 + tid) * JSPLIT + jh] = bi;
  }
}

__global__ void merge_kernel(const float* __restrict__ cand_val,
                             const int* __restrict__ cand_idx,
                             float* __restrict__ out) {
  int i = blockIdx.x * NTHR + threadIdx.x;
  float bv = INFINITY;
  int bi = 0x7fffffff;
#pragma unroll
  for (int s = 0; s < JSPLIT; ++s) {
    float v = cand_val[(size_t)i * JSPLIT + s];
    int ix = cand_idx[(size_t)i * JSPLIT + s];
    if (v < bv || (v == bv && ix < bi)) { bv = v; bi = ix; }
  }
  out[(size_t)i * NPTS + i] = 1.0f;   // self is always nearest (dist ~ 0)
  out[(size_t)i * NPTS + bi] = 1.0f;  // nearest other neighbor
}

extern "C" void kernel_launch(void* const* d_in, const int* in_sizes, int n_in,
                              void* d_out, int out_size, void* d_ws, size_t ws_size,
                              hipStream_t stream) {
  const float* X = (const float*)d_in[0];
  float* out = (float*)d_out;

  // Workspace: sq[N] | cand_val[N*JSPLIT] | cand_idx[N*JSPLIT]  (~1.1 MB)
  float* sq = (float*)d_ws;
  float* cand_val = sq + NPTS;
  int* cand_idx = (int*)(cand_val + (size_t)NPTS * JSPLIT);

  zero_kernel<<<65536, NTHR, 0, stream>>>((floatx4*)out);
  sq_kernel<<<NPTS / NTHR, NTHR, 0, stream>>>(X, sq);
  knn_kernel<<<(NPTS / BM) * JSPLIT, NTHR, 0, stream>>>(X, sq, cand_val, cand_idx);
  merge_kernel<<<NPTS / NTHR, NTHR, 0, stream>>>(cand_val, cand_idx, out);
}

// Round 6
// 27810.815 us; speedup vs baseline: 1.0063x; 1.0063x over previous
//
#include <hip/hip_runtime.h>
#include <math.h>

// KNNGraph(2) on N=16384 points, D=64, fp32.
// adjacency = I + one-hot(nearest other neighbor) per row.
// argmin_j (sq[j] - 2*dot(x_i,x_j)), j != i.
//
// R1-R5: 27 ms invariant to output stores (R3), register pressure (R4),
// software pipelining (R5); VALUBusy ~1.8% throughout; counters partly
// untrustworthy. R6 tests the two never-touched invariants:
//  (1) all blocks scanned identical B-tile sequences in lock-step
//      -> decorrelate via blockIdx remap + per-block j-tile rotation;
//  (2) output zero-fill through my own stores -> hipMemsetAsync instead.

#define NPTS 16384
#define DIM 64
#define BM 64           // rows per block
#define BN 64           // cols per j-tile
#define TM 4            // rows per thread
#define TN 4            // cols per thread
#define NTHR 256        // 16x16 thread layout
#define JSPLIT 8        // grid 2048 blocks
#define JRANGE (NPTS / JSPLIT)   // 2048
#define NJT (JRANGE / BN)        // 32 tiles
#define LS 68           // B-tile LDS row stride

__global__ void sq_kernel(const float* __restrict__ X, float* __restrict__ sqout) {
  int i = blockIdx.x * NTHR + threadIdx.x;
  const float4* x4 = (const float4*)(X + (size_t)i * DIM);
  float s = 0.f;
#pragma unroll
  for (int k = 0; k < DIM / 4; ++k) {
    float4 v = x4[k];
    s = fmaf(v.x, v.x, s); s = fmaf(v.y, v.y, s);
    s = fmaf(v.z, v.z, s); s = fmaf(v.w, v.w, s);
  }
  sqout[i] = s;
}

__global__ void knn_kernel(
    const float* __restrict__ X, const float* __restrict__ sqn,
    float* __restrict__ cand_val, int* __restrict__ cand_idx) {
  __shared__ float As[BM * DIM];        // 16 KB (A reads are broadcast: no pad)
  __shared__ float Bs[2][BN * LS];      // 2 x 17408 B
  __shared__ float sqt[2][BN];

  const int tid = threadIdx.x;
  const int tx = tid & 15;
  const int ty = tid >> 4;
  // Remap: adjacent blockIdx -> different i-panels (decorrelate A reads).
  const int ib = blockIdx.x & 255;
  const int jh = blockIdx.x >> 8;
  const int i0 = ib * BM;
  const int j0base = jh * JRANGE;
  // Per-block rotation of the j-tile visit order (decorrelate B streams).
  const int rot = (ib * 5) & (NJT - 1);

  // Stage A tile (BM x DIM): coalesced float4 loads.
  {
    const float4* src = (const float4*)(X + (size_t)i0 * DIM);
#pragma unroll
    for (int p = 0; p < 4; ++p) {
      int f4 = tid + NTHR * p;
      *(float4*)(&As[f4 * 4]) = src[f4];
    }
  }

  // Prefetch first (rotated) tile into registers, commit to buffer 0.
  float4 pre[4];
  float presq;
  {
    const int jt0 = rot;  // phys tile for logical t=0
    const float4* src = (const float4*)(X + (size_t)(j0base + jt0 * BN) * DIM);
#pragma unroll
    for (int p = 0; p < 4; ++p) pre[p] = src[tid + NTHR * p];
    presq = (tid < BN) ? sqn[j0base + jt0 * BN + tid] : 0.f;
  }
  {
    float* bnxt = &Bs[0][0];
#pragma unroll
    for (int p = 0; p < 4; ++p) {
      int f4 = tid + NTHR * p;
      int r = f4 >> 4, c = f4 & 15;
      *(float4*)(&bnxt[r * LS + c * 4]) = pre[p];
    }
    if (tid < BN) sqt[0][tid] = presq;
  }
  __syncthreads();

  float bestv[TM];
  int besti[TM];
#pragma unroll
  for (int mk = 0; mk < TM; ++mk) { bestv[mk] = INFINITY; besti[mk] = 0x7fffffff; }

  for (int t = 0; t < NJT; ++t) {
    const int cur = t & 1;
    const float* bcur = &Bs[cur][0];
    const float* scur = &sqt[cur][0];
    const int jt = (t + rot) & (NJT - 1);        // phys tile this iter
    const int j0 = j0base + jt * BN;

    // Prefetch next phys tile while computing this one.
    if (t + 1 < NJT) {
      const int jtn = (t + 1 + rot) & (NJT - 1);
      const float4* src = (const float4*)(X + (size_t)(j0base + jtn * BN) * DIM);
#pragma unroll
      for (int p = 0; p < 4; ++p) pre[p] = src[tid + NTHR * p];
      presq = (tid < BN) ? sqn[j0base + jtn * BN + tid] : 0.f;
    }

    float acc[TM][TN];
#pragma unroll
    for (int mk = 0; mk < TM; ++mk)
#pragma unroll
      for (int nk = 0; nk < TN; ++nk) acc[mk][nk] = 0.f;

#pragma unroll
    for (int d0 = 0; d0 < DIM; d0 += 4) {
      float4 a[TM], b[TN];
#pragma unroll
      for (int mk = 0; mk < TM; ++mk)
        a[mk] = *(const float4*)(&As[(ty + 16 * mk) * DIM + d0]);
#pragma unroll
      for (int nk = 0; nk < TN; ++nk)
        b[nk] = *(const float4*)(&bcur[(tx + 16 * nk) * LS + d0]);
#pragma unroll
      for (int mk = 0; mk < TM; ++mk)
#pragma unroll
        for (int nk = 0; nk < TN; ++nk) {
          acc[mk][nk] = fmaf(a[mk].x, b[nk].x, acc[mk][nk]);
          acc[mk][nk] = fmaf(a[mk].y, b[nk].y, acc[mk][nk]);
          acc[mk][nk] = fmaf(a[mk].z, b[nk].z, acc[mk][nk]);
          acc[mk][nk] = fmaf(a[mk].w, b[nk].w, acc[mk][nk]);
        }
    }

    // Argmin update; (v, idx) lexicographic makes visit order irrelevant.
#pragma unroll
    for (int nk = 0; nk < TN; ++nk) {
      const int j = j0 + tx + 16 * nk;
      const float sj = scur[tx + 16 * nk];
#pragma unroll
      for (int mk = 0; mk < TM; ++mk) {
        const int irow = i0 + ty + 16 * mk;
        float v = fmaf(-2.f, acc[mk][nk], sj);
        if (j != irow && (v < bestv[mk] || (v == bestv[mk] && j < besti[mk]))) {
          bestv[mk] = v;
          besti[mk] = j;
        }
      }
    }

    // Commit prefetched tile to the other buffer.
    if (t + 1 < NJT) {
      float* bnxt = &Bs[cur ^ 1][0];
#pragma unroll
      for (int p = 0; p < 4; ++p) {
        int f4 = tid + NTHR * p;
        int r = f4 >> 4, c = f4 & 15;
        *(float4*)(&bnxt[r * LS + c * 4]) = pre[p];
      }
      if (tid < BN) sqt[cur ^ 1][tid] = presq;
    }
    __syncthreads();
  }

  // Cross-thread reduction: row m = ty + 16*mk owned by its 16 tx-threads.
  float* rv = As;              // BM*16 floats = 4 KB
  int* ri = (int*)&Bs[0][0];   // BM*16 ints  = 4 KB
#pragma unroll
  for (int mk = 0; mk < TM; ++mk) {
    int m = ty + 16 * mk;
    rv[m * 16 + tx] = bestv[mk];
    ri[m * 16 + tx] = besti[mk];
  }
  __syncthreads();
  if (tid < BM) {
    float bv = INFINITY;
    int bi = 0x7fffffff;
#pragma unroll
    for (int t = 0; t < 16; ++t) {
      float v = rv[tid * 16 + t];
      int ix = ri[tid * 16 + t];
      if (v < bv || (v == bv && ix < bi)) { bv = v; bi = ix; }
    }
    cand_val[(size_t)(i0 + tid) * JSPLIT + jh] = bv;
    cand_idx[(size_t)(i0 + tid) * JSPLIT + jh] = bi;
  }
}

__global__ void merge_kernel(const float* __restrict__ cand_val,
                             const int* __restrict__ cand_idx,
                             float* __restrict__ out) {
  int i = blockIdx.x * NTHR + threadIdx.x;
  float bv = INFINITY;
  int bi = 0x7fffffff;
#pragma unroll
  for (int s = 0; s < JSPLIT; ++s) {
    float v = cand_val[(size_t)i * JSPLIT + s];
    int ix = cand_idx[(size_t)i * JSPLIT + s];
    if (v < bv || (v == bv && ix < bi)) { bv = v; bi = ix; }
  }
  out[(size_t)i * NPTS + i] = 1.0f;   // self is always nearest (dist ~ 0)
  out[(size_t)i * NPTS + bi] = 1.0f;  // nearest other neighbor
}

extern "C" void kernel_launch(void* const* d_in, const int* in_sizes, int n_in,
                              void* d_out, int out_size, void* d_ws, size_t ws_size,
                              hipStream_t stream) {
  const float* X = (const float*)d_in[0];
  float* out = (float*)d_out;

  // Workspace: sq[N] | cand_val[N*JSPLIT] | cand_idx[N*JSPLIT]  (~1.1 MB)
  float* sq = (float*)d_ws;
  float* cand_val = sq + NPTS;
  int* cand_idx = (int*)(cand_val + (size_t)NPTS * JSPLIT);

  // Zero the 1 GiB output via the runtime's fill path (graph-capturable).
  hipMemsetAsync(out, 0, (size_t)out_size * sizeof(float), stream);
  sq_kernel<<<NPTS / NTHR, NTHR, 0, stream>>>(X, sq);
  knn_kernel<<<(NPTS / BM) * JSPLIT, NTHR, 0, stream>>>(X, sq, cand_val, cand_idx);
  merge_kernel<<<NPTS / NTHR, NTHR, 0, stream>>>(cand_val, cand_idx, out);
}